// Round 1
// baseline (905.463 us; speedup 1.0000x reference)
//
#include <hip/hip_runtime.h>

#define B_    2
#define S_    8192
#define CIN_  64
#define COUT_ 64
#define K_    15
#define NS_   32

// ---------- wave-wide bitonic helpers: key = (dist, idx) lexicographic ----------
__device__ __forceinline__ void cmp_xchg(float& d, int& i, int j, bool up, int lane) {
  float od = __shfl_xor(d, j, 64);
  int   oi = __shfl_xor(i, j, 64);
  bool lower    = (lane & j) == 0;
  bool oless    = (od < d) || ((od == d) && (oi < i));
  bool ogreater = (od > d) || ((od == d) && (oi > i));
  bool take = (up == lower) ? oless : ogreater;
  if (take) { d = od; i = oi; }
}

__device__ __forceinline__ void sort64_asc(float& d, int& i, int lane) {
  #pragma unroll
  for (int k = 2; k <= 64; k <<= 1) {
    #pragma unroll
    for (int j = k >> 1; j > 0; j >>= 1)
      cmp_xchg(d, i, j, (lane & k) == 0, lane);
  }
}

__device__ __forceinline__ void merge64_asc(float& d, int& i, int lane) {
  #pragma unroll
  for (int j = 32; j > 0; j >>= 1)
    cmp_xchg(d, i, j, true, lane);
}

// ---------- Kernel A: exact top-64 neighbor selection, one wave per query ----------
__global__ __launch_bounds__(256) void kp_select(const float* __restrict__ xyz,
                                                 int* __restrict__ nbr) {
  __shared__ float xs[2048], ys[2048], zs[2048];
  __shared__ float bufd[4][128];
  __shared__ int   bufi[4][128];

  const int tid  = threadIdx.x;
  const int wid  = tid >> 6;
  const int lane = tid & 63;
  const int q    = blockIdx.x * 4 + wid;
  const int b    = q >> 13;          // q / S_
  const int s    = q & (S_ - 1);
  const float* base = xyz + (size_t)b * S_ * 3;

  const float qx = base[s * 3 + 0], qy = base[s * 3 + 1], qz = base[s * 3 + 2];
  const float sqq = qx * qx + qy * qy + qz * qz;   // matches ref sum(src**2)

  float rd = __builtin_inff();  // running top-64, ascending across lanes
  int   ri = -1;
  float rmax = __builtin_inff();
  int   cnt = 0;                // candidate-buffer fill (wave-uniform)

  for (int t = 0; t < 4; ++t) {
    __syncthreads();
    // stage 2048 points into planar LDS arrays (transposed on the fly)
    const float* src = base + t * 2048 * 3;
    for (int i = tid; i < 6144; i += 256) {
      float v = src[i];
      int p = i / 3;
      int c = i - p * 3;
      if (c == 0) xs[p] = v; else if (c == 1) ys[p] = v; else zs[p] = v;
    }
    __syncthreads();

    for (int ch = 0; ch < 32; ++ch) {
      int p = (ch << 6) + lane;
      float px = xs[p], py = ys[p], pz = zs[p];
      // reference formula/order: d = -2*dot; d += |q|^2; d += |p|^2
      float dot = qx * px + qy * py + qz * pz;
      float sqp = px * px + py * py + pz * pz;
      float d = -2.0f * dot;
      d = d + sqq;
      d = d + sqp;

      bool pred = d < rmax;
      unsigned long long m = __ballot(pred);
      if (m) {
        int pos = cnt + __popcll(m & ((1ull << lane) - 1ull));
        if (pred) { bufd[wid][pos] = d; bufi[wid][pos] = (t << 11) + p; }
        cnt += (int)__popcll(m);
        while (cnt >= 64) {
          cnt -= 64;
          asm volatile("s_waitcnt lgkmcnt(0)" ::: "memory");
          float cd = bufd[wid][cnt + lane];
          int   ci = bufi[wid][cnt + lane];
          sort64_asc(cd, ci, lane);
          // reverse chunk -> descending; elementwise-min with R -> bitonic;
          // 6-stage merge restores ascending = 64 smallest of union
          float od = __shfl_xor(cd, 63, 64);
          int   oi = __shfl_xor(ci, 63, 64);
          bool oless = (od < rd) || ((od == rd) && (oi < ri));
          if (oless) { rd = od; ri = oi; }
          merge64_asc(rd, ri, lane);
          rmax = __shfl(rd, 63, 64);
        }
      }
    }
  }

  if (cnt > 0) {  // final partial flush (pad with +inf)
    asm volatile("s_waitcnt lgkmcnt(0)" ::: "memory");
    float cd = (lane < cnt) ? bufd[wid][lane] : __builtin_inff();
    int   ci = (lane < cnt) ? bufi[wid][lane] : 0x7fffffff;
    sort64_asc(cd, ci, lane);
    float od = __shfl_xor(cd, 63, 64);
    int   oi = __shfl_xor(ci, 63, 64);
    bool oless = (od < rd) || ((od == rd) && (oi < ri));
    if (oless) { rd = od; ri = oi; }
    merge64_asc(rd, ri, lane);
  }

  // lanes 0..31 hold the 32 nearest (stable-sort order); apply radius mask
  int r0 = __shfl(ri, 0, 64);
  int w  = (rd > 1.0f) ? r0 : ri;   // mask: d > RADIUS^2 -> nearest idx
  if (lane < NS_) nbr[(size_t)q * NS_ + lane] = w;
}

// ---------- Kernel W: transpose weights [k][c][o] -> [k][o][c] ----------
__global__ void kp_transpose_w(const float* __restrict__ w, float* __restrict__ wt) {
  int idx = blockIdx.x * 256 + threadIdx.x;   // < 61440
  int k = idx >> 12;
  int r = idx & 4095;
  int c = r >> 6;
  int o = r & 63;
  wt[(k << 12) + (o << 6) + c] = w[idx];
}

// ---------- Kernel B: influence aggregation + contraction, one wave per query ----------
__global__ __launch_bounds__(256) void kp_gather(
    const float* __restrict__ xyz, const float* __restrict__ feat,
    const float* __restrict__ kp, const float* __restrict__ wt,
    const int* __restrict__ nbr, float* __restrict__ out) {
  __shared__ float w_lds[4096];          // one k-slice of Wt, XOR-swizzled
  __shared__ float agg_lds[4][960];      // per-wave agg[k][c]

  const int tid  = threadIdx.x;
  const int wid  = tid >> 6;
  const int lane = tid & 63;
  const int q    = blockIdx.x * 4 + wid;
  const int b    = q >> 13;
  const int s    = q & (S_ - 1);
  const float* bx = xyz + (size_t)b * S_ * 3;
  const float qx = bx[s * 3 + 0], qy = bx[s * 3 + 1], qz = bx[s * 3 + 2];

  float kx = 0.f, ky = 0.f, kz = 0.f;
  if (lane < K_) { kx = kp[lane * 3 + 0]; ky = kp[lane * 3 + 1]; kz = kp[lane * 3 + 2]; }

  // prefetch the 32 neighbor indices + their coords into lanes 0..31
  int nl = 0;
  if (lane < NS_) nl = nbr[(size_t)q * NS_ + lane];
  float nx = 0.f, ny = 0.f, nz = 0.f;
  if (lane < NS_) { nx = bx[nl * 3 + 0]; ny = bx[nl * 3 + 1]; nz = bx[nl * 3 + 2]; }

  const float* fb = feat + (size_t)b * S_ * CIN_;
  float agg[K_];
  #pragma unroll
  for (int k = 0; k < K_; ++k) agg[k] = 0.f;

  #pragma unroll 4
  for (int j = 0; j < NS_; ++j) {
    int   n  = __shfl(nl, j, 64);
    float rx = __shfl(nx, j, 64) - qx;
    float ry = __shfl(ny, j, 64) - qy;
    float rz = __shfl(nz, j, 64) - qz;
    float infl = 0.f;
    if (lane < K_) {
      float dx = rx - kx, dy = ry - ky, dz = rz - kz;
      float sq = dx * dx + dy * dy + dz * dz;
      sq = fmaxf(sq, 0.f);
      // RADIUS + 1e-8 rounds to 1.0f in f32 -> divide is exact no-op
      infl = fmaxf(1.0f - sqrtf(sq + 1e-8f), 0.f);
    }
    float f = fb[(size_t)n * CIN_ + lane];
    #pragma unroll
    for (int k = 0; k < K_; ++k)
      agg[k] = fmaf(__shfl(infl, k, 64), f, agg[k]);
  }

  #pragma unroll
  for (int k = 0; k < K_; ++k) agg_lds[wid][k * 64 + lane] = agg[k];

  float acc = 0.f;
  for (int kt = 0; kt < K_; ++kt) {
    __syncthreads();
    // stage Wt[kt] (layout [o][c]) with 4-float-group XOR swizzle: g' = g ^ (o&15)
    for (int i = tid; i < 4096; i += 256) {
      int o = i >> 6;
      int c = i & 63;
      int cs = (c & 3) | ((((c >> 2) ^ o) & 15) << 2);
      w_lds[(o << 6) + cs] = wt[(kt << 12) + i];
    }
    __syncthreads();
    #pragma unroll
    for (int gs = 0; gs < 16; ++gs) {
      const float4 wv = *(const float4*)&w_lds[(lane << 6) + (gs << 2)];
      int g = gs ^ (lane & 15);
      const float4 av = *(const float4*)&agg_lds[wid][kt * 64 + (g << 2)];
      acc += wv.x * av.x;
      acc += wv.y * av.y;
      acc += wv.z * av.z;
      acc += wv.w * av.w;
    }
  }
  out[(size_t)q * COUT_ + lane] = acc;
}

extern "C" void kernel_launch(void* const* d_in, const int* in_sizes, int n_in,
                              void* d_out, int out_size, void* d_ws, size_t ws_size,
                              hipStream_t stream) {
  const float* xyz  = (const float*)d_in[0];
  const float* feat = (const float*)d_in[1];
  const float* w    = (const float*)d_in[2];
  const float* kp   = (const float*)d_in[3];

  float* out = (float*)d_out;                    // [B*S*3 xyz copy][B*S*64 out]
  float* wt  = (float*)d_ws;                     // 61440 floats
  int*   nbr = (int*)((char*)d_ws + 61440 * sizeof(float));  // 16384*32 ints

  // output 0: passthrough of query_xyz
  hipMemcpyAsync(out, xyz, (size_t)B_ * S_ * 3 * sizeof(float),
                 hipMemcpyDeviceToDevice, stream);

  kp_transpose_w<<<240, 256, 0, stream>>>(w, wt);
  kp_select<<<(B_ * S_) / 4, 256, 0, stream>>>(xyz, nbr);
  kp_gather<<<(B_ * S_) / 4, 256, 0, stream>>>(xyz, feat, kp, wt, nbr,
                                               out + (size_t)B_ * S_ * 3);
}

// Round 3
// 417.935 us; speedup vs baseline: 2.1665x; 2.1665x over previous
//
#include <hip/hip_runtime.h>

#define B_    2
#define S_    8192
#define CIN_  64
#define COUT_ 64
#define K_    15
#define NS_   32

typedef unsigned long long u64;
typedef unsigned int u32;
typedef unsigned short u16;

__device__ __forceinline__ u32 f2bf(float x){            // RNE f32 -> bf16 bits
  u32 u = __float_as_uint(x);
  return (u + 0x7FFFu + ((u >> 16) & 1u)) >> 16;
}
__device__ __forceinline__ float bflo(u32 p){ return __uint_as_float(p << 16); }
__device__ __forceinline__ float bfhi(u32 p){ return __uint_as_float(p & 0xFFFF0000u); }

// ---------------- u64 wave-wide bitonic helpers (key = (mapped_d<<13)|idx) ----------------
__device__ __forceinline__ void cx(u64 &k, int j, bool up, int lane){
  u64 o = __shfl_xor(k, j, 64);
  bool lower = (lane & j) == 0;
  bool take = (up == lower) ? (o < k) : (o > k);
  if (take) k = o;
}
__device__ __forceinline__ void sort64(u64 &k, int lane){
  #pragma unroll
  for (int kk = 2; kk <= 64; kk <<= 1){
    #pragma unroll
    for (int j = kk >> 1; j > 0; j >>= 1) cx(k, j, (lane & kk) == 0, lane);
  }
}
__device__ __forceinline__ void merge64(u64 &k, int lane){
  #pragma unroll
  for (int j = 32; j > 0; j >>= 1) cx(k, j, true, lane);
}

// ---------------- Kernel A: exact top-64 selection, 4 queries per wave ----------------
__global__ __launch_bounds__(256) void kp_select(const float* __restrict__ xyz,
                                                 int* __restrict__ nbr){
  __shared__ float pts[2048 * 4];          // (x,y,z,unused) per point, 32 KB
  __shared__ u64 buf[4][4][128];           // per-wave per-query candidate buffer, 16 KB

  const int tid = threadIdx.x, w = tid >> 6, lane = tid & 63;
  const int qbase = blockIdx.x * 16;       // 16 queries per block, same batch
  const int b = qbase >> 13;
  const float* base = xyz + (size_t)b * S_ * 3;

  float qx[4], qy[4], qz[4], sqq[4];
  #pragma unroll
  for (int i = 0; i < 4; ++i){
    int s = (qbase + w * 4 + i) & (S_ - 1);
    qx[i] = base[s*3]; qy[i] = base[s*3+1]; qz[i] = base[s*3+2];
    sqq[i] = qx[i]*qx[i] + qy[i]*qy[i] + qz[i]*qz[i];
  }
  u64 rkey[4] = {~0ull, ~0ull, ~0ull, ~0ull};   // running top-64 (ascending across lanes)
  u64 kmax[4] = {~0ull, ~0ull, ~0ull, ~0ull};
  int cnt[4]  = {0, 0, 0, 0};

  for (int t = 0; t < 4; ++t){
    __syncthreads();
    const float* src = base + t * 2048 * 3;
    for (int i = tid; i < 6144; i += 256){   // coalesced read, scattered float4 repack
      int p = i / 3, c = i - p * 3;
      pts[p * 4 + c] = src[i];
    }
    __syncthreads();

    for (int ch = 0; ch < 32; ++ch){
      float4 v = ((const float4*)pts)[ch * 64 + lane];
      float sqp = v.x*v.x + v.y*v.y + v.z*v.z;
      int pidx = t * 2048 + ch * 64 + lane;
      #pragma unroll
      for (int i = 0; i < 4; ++i){
        float dot = qx[i]*v.x + qy[i]*v.y + qz[i]*v.z;
        float d = -2.0f * dot; d = d + sqq[i]; d = d + sqp;   // reference formula/order
        u32 md = __float_as_uint(d);
        md ^= (u32)((int)md >> 31) | 0x80000000u;            // monotonic float->uint map
        u64 key = ((u64)md << 13) | (u32)pidx;
        bool pred = key < kmax[i];
        u64 m = __ballot(pred);
        if (m){
          int pos = cnt[i] + (int)__popcll(m & ((1ull << lane) - 1ull));
          if (pred) buf[w][i][pos] = key;
          cnt[i] += (int)__popcll(m);
          while (cnt[i] >= 64){
            cnt[i] -= 64;
            asm volatile("s_waitcnt lgkmcnt(0)" ::: "memory");
            u64 ck = buf[w][i][cnt[i] + lane];
            sort64(ck, lane);
            u64 rev = __shfl_xor(ck, 63, 64);      // descending chunk
            if (rev < rkey[i]) rkey[i] = rev;      // elementwise min -> bitonic
            merge64(rkey[i], lane);                // 64 smallest of union
            kmax[i] = __shfl(rkey[i], 63, 64);
          }
        }
      }
    }
  }

  #pragma unroll
  for (int i = 0; i < 4; ++i){
    if (cnt[i] > 0){                               // final partial flush
      asm volatile("s_waitcnt lgkmcnt(0)" ::: "memory");
      u64 ck = (lane < cnt[i]) ? buf[w][i][lane] : ~0ull;
      sort64(ck, lane);
      u64 rev = __shfl_xor(ck, 63, 64);
      if (rev < rkey[i]) rkey[i] = rev;
      merge64(rkey[i], lane);
    }
    u32 md  = (u32)(rkey[i] >> 13);
    int idx = (int)(rkey[i] & 8191u);
    int i0  = __shfl(idx, 0, 64);
    int wi  = (md > 0xBF800000u) ? i0 : idx;       // d > RADIUS^2 -> nearest idx
    if (lane < NS_) nbr[(size_t)(qbase + w * 4 + i) * NS_ + lane] = wi;
  }
}

// ---------------- Kernel W: convert weights [k][c][o] f32 -> bf16 (same layout) ----------------
__global__ void w_cvt(const float* __restrict__ w, u16* __restrict__ wt){
  int i = blockIdx.x * 256 + threadIdx.x;          // 240*256 == 61440 exact
  wt[i] = (u16)f2bf(w[i]);
}

// ---------------- Kernel B: aggregation (readlane influence) + GEMM contraction ----------------
__global__ __launch_bounds__(256) void kp_gather(
    const float* __restrict__ xyz, const float* __restrict__ feat,
    const float* __restrict__ kp, const u16* __restrict__ wt,
    const int* __restrict__ nbr, float* __restrict__ outp){
  __shared__ u32 aggt[960 * 9];                    // [kc][8 q-pairs + pad], bf16x2, 34.6 KB
  __shared__ float red[4 * 1024];                  // k-split partials, 16 KB

  const int tid = threadIdx.x, w = tid >> 6, lane = tid & 63;
  const int qbase = blockIdx.x * 16;
  const int b = qbase >> 13;
  const float* bx = xyz + (size_t)b * S_ * 3;
  const float* fb = feat + (size_t)b * S_ * CIN_;

  const int kk = lane & 15;
  float kx = 0.f, ky = 0.f, kz = 0.f;
  if (kk < 15){ kx = kp[kk*3]; ky = kp[kk*3+1]; kz = kp[kk*3+2]; }

  float agg0[15], agg1[15];

  auto do_q = [&](int ql, float (&agg)[15]){
    const int q = qbase + ql;
    const int s = q & (S_ - 1);
    const float qx = bx[s*3], qy = bx[s*3+1], qz = bx[s*3+2];
    int nl = 0; float nx = 0.f, ny = 0.f, nz = 0.f;
    if (lane < NS_){
      nl = nbr[(size_t)q * NS_ + lane];
      nx = bx[nl*3]; ny = bx[nl*3+1]; nz = bx[nl*3+2];
    }
    const float rx = nx - qx, ry = ny - qy, rz = nz - qz;

    // influences, (j,k)-lane-parallel: lane = ((j&3)<<4)|k
    float infl[8];
    #pragma unroll
    for (int jg = 0; jg < 8; ++jg){
      int jj = jg * 4 + (lane >> 4);
      float ax = __shfl(rx, jj, 64), ay = __shfl(ry, jj, 64), az = __shfl(rz, jj, 64);
      float dx = ax - kx, dy = ay - ky, dz = az - kz;
      float sq = dx*dx + dy*dy + dz*dz;
      sq = fmaxf(sq, 0.0f);
      infl[jg] = fmaxf(1.0f - sqrtf(sq + 1e-8f), 0.0f);   // /(R+1e-8) == /1.0f in f32
    }
    #pragma unroll
    for (int k = 0; k < 15; ++k) agg[k] = 0.0f;
    #pragma unroll
    for (int jg = 0; jg < 8; ++jg){
      int n0 = __shfl(nl, jg*4+0, 64); float f0 = fb[(size_t)n0 * CIN_ + lane];
      int n1 = __shfl(nl, jg*4+1, 64); float f1 = fb[(size_t)n1 * CIN_ + lane];
      int n2 = __shfl(nl, jg*4+2, 64); float f2 = fb[(size_t)n2 * CIN_ + lane];
      int n3 = __shfl(nl, jg*4+3, 64); float f3 = fb[(size_t)n3 * CIN_ + lane];
      u32 iv = __float_as_uint(infl[jg]);
      #pragma unroll
      for (int k = 0; k < 15; ++k){
        float s0 = __uint_as_float(__builtin_amdgcn_readlane(iv, k));       // scalar ops:
        float s1 = __uint_as_float(__builtin_amdgcn_readlane(iv, 16 + k));  // no DS pipe
        float s2 = __uint_as_float(__builtin_amdgcn_readlane(iv, 32 + k));
        float s3 = __uint_as_float(__builtin_amdgcn_readlane(iv, 48 + k));
        agg[k] = fmaf(s0, f0, agg[k]);
        agg[k] = fmaf(s1, f1, agg[k]);
        agg[k] = fmaf(s2, f2, agg[k]);
        agg[k] = fmaf(s3, f3, agg[k]);
      }
    }
  };

  #pragma unroll
  for (int pair = 0; pair < 2; ++pair){
    do_q(w * 4 + pair * 2 + 0, agg0);
    do_q(w * 4 + pair * 2 + 1, agg1);
    #pragma unroll
    for (int k = 0; k < 15; ++k){
      u32 pk = (f2bf(agg1[k]) << 16) | f2bf(agg0[k]);
      aggt[(k * 64 + lane) * 9 + (w * 2 + pair)] = pk;   // stride 9 dwords: conflict-free
    }
  }
  __syncthreads();

  // contraction: out[16q x 64o] = agg[16q x 960] @ W[960 x 64], thread tile 2q x 8o, 4-way k-split
  const int ks = tid >> 6;
  const int qp = lane >> 3;       // q-pair 0..7
  const int oc = lane & 7;        // o-octet 0..7
  float acc0[8], acc1[8];
  #pragma unroll
  for (int i = 0; i < 8; ++i){ acc0[i] = 0.f; acc1[i] = 0.f; }
  const uint4* wp = (const uint4*)wt;
  #pragma unroll 4
  for (int kc = ks * 240; kc < ks * 240 + 240; ++kc){
    u32 ap = aggt[kc * 9 + qp];                     // broadcast among 8 oc-threads
    float a0 = bflo(ap), a1 = bfhi(ap);
    uint4 wv = wp[kc * 8 + oc];                     // 8 bf16 from L2-resident W
    float wr[8];
    wr[0] = bflo(wv.x); wr[1] = bfhi(wv.x); wr[2] = bflo(wv.y); wr[3] = bfhi(wv.y);
    wr[4] = bflo(wv.z); wr[5] = bfhi(wv.z); wr[6] = bflo(wv.w); wr[7] = bfhi(wv.w);
    #pragma unroll
    for (int i = 0; i < 8; ++i){
      acc0[i] = fmaf(a0, wr[i], acc0[i]);
      acc1[i] = fmaf(a1, wr[i], acc1[i]);
    }
  }
  float* rw = &red[ks * 1024 + (qp * 2) * 64 + oc * 8];
  #pragma unroll
  for (int i = 0; i < 8; ++i) rw[i] = acc0[i];
  #pragma unroll
  for (int i = 0; i < 8; ++i) rw[64 + i] = acc1[i];
  __syncthreads();

  const int flat = tid * 4;
  float4 s0 = *(const float4*)&red[flat];
  float4 s1 = *(const float4*)&red[1024 + flat];
  float4 s2 = *(const float4*)&red[2048 + flat];
  float4 s3 = *(const float4*)&red[3072 + flat];
  float4 r;
  r.x = (s0.x + s1.x) + (s2.x + s3.x);
  r.y = (s0.y + s1.y) + (s2.y + s3.y);
  r.z = (s0.z + s1.z) + (s2.z + s3.z);
  r.w = (s0.w + s1.w) + (s2.w + s3.w);
  const int q_l = flat >> 6, o = flat & 63;
  *(float4*)&outp[(size_t)(qbase + q_l) * COUT_ + o] = r;
}

extern "C" void kernel_launch(void* const* d_in, const int* in_sizes, int n_in,
                              void* d_out, int out_size, void* d_ws, size_t ws_size,
                              hipStream_t stream) {
  const float* xyz  = (const float*)d_in[0];
  const float* feat = (const float*)d_in[1];
  const float* w    = (const float*)d_in[2];
  const float* kp   = (const float*)d_in[3];

  float* out = (float*)d_out;                         // [B*S*3 xyz][B*S*64 out]
  u16*   wt  = (u16*)d_ws;                            // 61440 bf16 (122880 B)
  int*   nbr = (int*)((char*)d_ws + 131072);          // 16384*32 ints

  hipMemcpyAsync(out, xyz, (size_t)B_ * S_ * 3 * sizeof(float),
                 hipMemcpyDeviceToDevice, stream);

  w_cvt<<<240, 256, 0, stream>>>(w, wt);
  kp_select<<<(B_ * S_) / 16, 256, 0, stream>>>(xyz, nbr);
  kp_gather<<<(B_ * S_) / 16, 256, 0, stream>>>(xyz, feat, kp, wt, nbr,
                                                out + (size_t)B_ * S_ * 3);
}

// Round 4
// 279.525 us; speedup vs baseline: 3.2393x; 1.4952x over previous
//
#include <hip/hip_runtime.h>

#define B_    2
#define S_    8192
#define CIN_  64
#define COUT_ 64
#define K_    15
#define NS_   32

typedef unsigned long long u64;
typedef unsigned int u32;
typedef unsigned short u16;

__device__ __forceinline__ u32 f2bf(float x){            // RNE f32 -> bf16 bits
  u32 u = __float_as_uint(x);
  return (u + 0x7FFFu + ((u >> 16) & 1u)) >> 16;
}
__device__ __forceinline__ float bflo(u32 p){ return __uint_as_float(p << 16); }
__device__ __forceinline__ float bfhi(u32 p){ return __uint_as_float(p & 0xFFFF0000u); }

// ---------------- u64 wave-wide bitonic helpers (key = (mapped_d<<13)|idx) ----------------
__device__ __forceinline__ void cx(u64 &k, int j, bool up, int lane){
  u64 o = __shfl_xor(k, j, 64);
  bool lower = (lane & j) == 0;
  bool take = (up == lower) ? (o < k) : (o > k);
  if (take) k = o;
}
__device__ __forceinline__ void sort64(u64 &k, int lane){
  #pragma unroll
  for (int kk = 2; kk <= 64; kk <<= 1){
    #pragma unroll
    for (int j = kk >> 1; j > 0; j >>= 1) cx(k, j, (lane & kk) == 0, lane);
  }
}
__device__ __forceinline__ void merge32(u64 &k, int lane){   // lanes 0..31 carry payload
  #pragma unroll
  for (int j = 16; j > 0; j >>= 1) cx(k, j, true, lane);
}

// ---------------- Kernel A: exact top-32 selection, 4 queries per wave, no point staging ----------------
__global__ __launch_bounds__(256) void kp_select(const float* __restrict__ xyz,
                                                 int* __restrict__ nbr){
  __shared__ u64 buf[4][4][128];           // per-wave per-query candidate buffer, 16 KB only

  const int tid = threadIdx.x, w = tid >> 6, lane = tid & 63;
  const int qbase = blockIdx.x * 16 + w * 4;
  const int b = qbase >> 13;
  const float* base = xyz + (size_t)b * S_ * 3;

  float qx[4], qy[4], qz[4], sqq[4];
  #pragma unroll
  for (int i = 0; i < 4; ++i){
    int s = (qbase + i) & (S_ - 1);
    qx[i] = base[s*3]; qy[i] = base[s*3+1]; qz[i] = base[s*3+2];
    sqq[i] = qx[i]*qx[i] + qy[i]*qy[i] + qz[i]*qz[i];
  }

  u64 rkey[4] = {~0ull, ~0ull, ~0ull, ~0ull};   // lanes 0..31: running top-32 ascending
  u32 kmd[4]  = {0xFFFFFFFFu, 0xFFFFFFFFu, 0xFFFFFFFFu, 0xFFFFFFFFu};
  int cnt[4]  = {0, 0, 0, 0};

  // L2-resident point stream with next-chunk prefetch (xyz = 96 KB/batch)
  float cxv = base[lane*3], cyv = base[lane*3+1], czv = base[lane*3+2];

  for (int ch = 0; ch < 128; ++ch){
    float nxv = cxv, nyv = cyv, nzv = czv;
    if (ch < 127){
      int p = (ch + 1) * 64 + lane;
      nxv = base[p*3]; nyv = base[p*3+1]; nzv = base[p*3+2];
    }
    float sqp = cxv*cxv + cyv*cyv + czv*czv;
    int pidx = ch * 64 + lane;
    #pragma unroll
    for (int i = 0; i < 4; ++i){
      float dot = qx[i]*cxv + qy[i]*cyv + qz[i]*czv;
      float d = -2.0f * dot; d = d + sqq[i]; d = d + sqp;   // reference formula/order
      u32 md = __float_as_uint(d);
      md ^= (u32)((int)md >> 31) | 0x80000000u;            // monotonic float->uint map
      bool pred = md <= kmd[i];                            // u32 filter, ties pass (safe)
      u64 m = __ballot(pred);
      if (m){
        int pos = cnt[i] + (int)__popcll(m & ((1ull << lane) - 1ull));
        if (pred) buf[w][i][pos] = ((u64)md << 13) | (u32)pidx;
        cnt[i] += (int)__popcll(m);
        if (cnt[i] >= 64){
          cnt[i] -= 64;
          asm volatile("s_waitcnt lgkmcnt(0)" ::: "memory");
          u64 ck = buf[w][i][cnt[i] + lane];
          sort64(ck, lane);                                // chunk ascending
          u64 rev = __shfl(ck, (31 - lane) & 63, 64);      // best-32 reversed into lanes 0..31
          if (rev < rkey[i]) rkey[i] = rev;                // elementwise min -> bitonic
          merge32(rkey[i], lane);                          // 32 smallest of union
          u64 k31 = __shfl(rkey[i], 31, 64);
          kmd[i] = (u32)(k31 >> 13);
        }
      }
    }
    cxv = nxv; cyv = nyv; czv = nzv;
  }

  #pragma unroll
  for (int i = 0; i < 4; ++i){
    if (cnt[i] > 0){                               // final partial flush
      asm volatile("s_waitcnt lgkmcnt(0)" ::: "memory");
      u64 ck = (lane < cnt[i]) ? buf[w][i][lane] : ~0ull;
      sort64(ck, lane);
      u64 rev = __shfl(ck, (31 - lane) & 63, 64);
      if (rev < rkey[i]) rkey[i] = rev;
      merge32(rkey[i], lane);
    }
    u32 md  = (u32)(rkey[i] >> 13);
    int idx = (int)(rkey[i] & 8191u);
    int i0  = __shfl(idx, 0, 64);
    int wi  = (md > 0xBF800000u) ? i0 : idx;       // d > RADIUS^2 -> nearest idx
    if (lane < NS_) nbr[(size_t)(qbase + i) * NS_ + lane] = wi;
  }
}

// ---------------- Kernel W: convert weights [k][c][o] f32 -> bf16 (same layout) ----------------
__global__ void w_cvt(const float* __restrict__ w, u16* __restrict__ wt){
  int i = blockIdx.x * 256 + threadIdx.x;          // 240*256 == 61440 exact
  wt[i] = (u16)f2bf(w[i]);
}

// ---------------- Kernel B: aggregation (readlane influence) + GEMM contraction ----------------
__global__ __launch_bounds__(256) void kp_gather(
    const float* __restrict__ xyz, const float* __restrict__ feat,
    const float* __restrict__ kp, const u16* __restrict__ wt,
    const int* __restrict__ nbr, float* __restrict__ outp){
  __shared__ u32 aggt[960 * 9];                    // [kc][8 q-pairs + pad], bf16x2, 34.6 KB
  float* red = (float*)aggt;                       // k-split partials alias (after barrier)

  const int tid = threadIdx.x, w = tid >> 6, lane = tid & 63;
  const int qbase = blockIdx.x * 16;
  const int b = qbase >> 13;
  const float* bx = xyz + (size_t)b * S_ * 3;
  const float* fb = feat + (size_t)b * S_ * CIN_;

  const int kk = lane & 15;
  float kx = 0.f, ky = 0.f, kz = 0.f;
  if (kk < 15){ kx = kp[kk*3]; ky = kp[kk*3+1]; kz = kp[kk*3+2]; }

  float agg0[15], agg1[15];

  auto do_q = [&](int ql, float (&agg)[15]){
    const int q = qbase + ql;
    const int s = q & (S_ - 1);
    const float qx = bx[s*3], qy = bx[s*3+1], qz = bx[s*3+2];
    int nl = 0; float nx = 0.f, ny = 0.f, nz = 0.f;
    if (lane < NS_){
      nl = nbr[(size_t)q * NS_ + lane];
      nx = bx[nl*3]; ny = bx[nl*3+1]; nz = bx[nl*3+2];
    }
    const float rx = nx - qx, ry = ny - qy, rz = nz - qz;

    // influences, (j,k)-lane-parallel: lane = ((j&3)<<4)|k
    float infl[8];
    #pragma unroll
    for (int jg = 0; jg < 8; ++jg){
      int jj = jg * 4 + (lane >> 4);
      float ax = __shfl(rx, jj, 64), ay = __shfl(ry, jj, 64), az = __shfl(rz, jj, 64);
      float dx = ax - kx, dy = ay - ky, dz = az - kz;
      float sq = dx*dx + dy*dy + dz*dz;
      sq = fmaxf(sq, 0.0f);
      infl[jg] = fmaxf(1.0f - sqrtf(sq + 1e-8f), 0.0f);   // /(R+1e-8) == /1.0f in f32
    }
    #pragma unroll
    for (int k = 0; k < 15; ++k) agg[k] = 0.0f;
    #pragma unroll
    for (int jg = 0; jg < 8; ++jg){
      int n0 = __shfl(nl, jg*4+0, 64); float f0 = fb[(size_t)n0 * CIN_ + lane];
      int n1 = __shfl(nl, jg*4+1, 64); float f1 = fb[(size_t)n1 * CIN_ + lane];
      int n2 = __shfl(nl, jg*4+2, 64); float f2 = fb[(size_t)n2 * CIN_ + lane];
      int n3 = __shfl(nl, jg*4+3, 64); float f3 = fb[(size_t)n3 * CIN_ + lane];
      u32 iv = __float_as_uint(infl[jg]);
      #pragma unroll
      for (int k = 0; k < 15; ++k){
        float s0 = __uint_as_float(__builtin_amdgcn_readlane(iv, k));       // scalar ops:
        float s1 = __uint_as_float(__builtin_amdgcn_readlane(iv, 16 + k));  // no DS pipe
        float s2 = __uint_as_float(__builtin_amdgcn_readlane(iv, 32 + k));
        float s3 = __uint_as_float(__builtin_amdgcn_readlane(iv, 48 + k));
        agg[k] = fmaf(s0, f0, agg[k]);
        agg[k] = fmaf(s1, f1, agg[k]);
        agg[k] = fmaf(s2, f2, agg[k]);
        agg[k] = fmaf(s3, f3, agg[k]);
      }
    }
  };

  #pragma unroll
  for (int pair = 0; pair < 2; ++pair){
    do_q(w * 4 + pair * 2 + 0, agg0);
    do_q(w * 4 + pair * 2 + 1, agg1);
    #pragma unroll
    for (int k = 0; k < 15; ++k){
      u32 pk = (f2bf(agg1[k]) << 16) | f2bf(agg0[k]);
      aggt[(k * 64 + lane) * 9 + (w * 2 + pair)] = pk;   // stride 9 dwords: conflict-free
    }
  }
  __syncthreads();

  // contraction: out[16q x 64o] = agg[16q x 960] @ W[960 x 64], thread tile 2q x 8o, 4-way k-split
  const int ks = tid >> 6;
  const int qp = lane >> 3;       // q-pair 0..7
  const int oc = lane & 7;        // o-octet 0..7
  float acc0[8], acc1[8];
  #pragma unroll
  for (int i = 0; i < 8; ++i){ acc0[i] = 0.f; acc1[i] = 0.f; }
  const uint4* wp = (const uint4*)wt;
  #pragma unroll 4
  for (int kc = ks * 240; kc < ks * 240 + 240; ++kc){
    u32 ap = aggt[kc * 9 + qp];                     // broadcast among 8 oc-threads
    float a0 = bflo(ap), a1 = bfhi(ap);
    uint4 wv = wp[kc * 8 + oc];                     // 8 bf16 from L2-resident W
    float wr[8];
    wr[0] = bflo(wv.x); wr[1] = bfhi(wv.x); wr[2] = bflo(wv.y); wr[3] = bfhi(wv.y);
    wr[4] = bflo(wv.z); wr[5] = bfhi(wv.z); wr[6] = bflo(wv.w); wr[7] = bfhi(wv.w);
    #pragma unroll
    for (int i = 0; i < 8; ++i){
      acc0[i] = fmaf(a0, wr[i], acc0[i]);
      acc1[i] = fmaf(a1, wr[i], acc1[i]);
    }
  }
  __syncthreads();                                  // all aggt reads done -> reuse as red
  float* rw = &red[ks * 1024 + (qp * 2) * 64 + oc * 8];
  #pragma unroll
  for (int i = 0; i < 8; ++i) rw[i] = acc0[i];
  #pragma unroll
  for (int i = 0; i < 8; ++i) rw[64 + i] = acc1[i];
  __syncthreads();

  const int flat = tid * 4;
  float4 s0 = *(const float4*)&red[flat];
  float4 s1 = *(const float4*)&red[1024 + flat];
  float4 s2 = *(const float4*)&red[2048 + flat];
  float4 s3 = *(const float4*)&red[3072 + flat];
  float4 r;
  r.x = (s0.x + s1.x) + (s2.x + s3.x);
  r.y = (s0.y + s1.y) + (s2.y + s3.y);
  r.z = (s0.z + s1.z) + (s2.z + s3.z);
  r.w = (s0.w + s1.w) + (s2.w + s3.w);
  const int q_l = flat >> 6, o = flat & 63;
  *(float4*)&outp[(size_t)(qbase + q_l) * COUT_ + o] = r;
}

extern "C" void kernel_launch(void* const* d_in, const int* in_sizes, int n_in,
                              void* d_out, int out_size, void* d_ws, size_t ws_size,
                              hipStream_t stream) {
  const float* xyz  = (const float*)d_in[0];
  const float* feat = (const float*)d_in[1];
  const float* w    = (const float*)d_in[2];
  const float* kp   = (const float*)d_in[3];

  float* out = (float*)d_out;                         // [B*S*3 xyz][B*S*64 out]
  u16*   wt  = (u16*)d_ws;                            // 61440 bf16 (122880 B)
  int*   nbr = (int*)((char*)d_ws + 131072);          // 16384*32 ints

  hipMemcpyAsync(out, xyz, (size_t)B_ * S_ * 3 * sizeof(float),
                 hipMemcpyDeviceToDevice, stream);

  w_cvt<<<240, 256, 0, stream>>>(w, wt);
  kp_select<<<(B_ * S_) / 16, 256, 0, stream>>>(xyz, nbr);
  kp_gather<<<(B_ * S_) / 16, 256, 0, stream>>>(xyz, feat, kp, wt, nbr,
                                                out + (size_t)B_ * S_ * 3);
}

// Round 7
// 232.506 us; speedup vs baseline: 3.8944x; 1.2022x over previous
//
#include <hip/hip_runtime.h>

#define B_    2
#define S_    8192
#define CIN_  64
#define COUT_ 64
#define K_    15
#define NS_   32

typedef unsigned long long u64;
typedef unsigned int u32;
typedef unsigned short u16;
typedef __attribute__((ext_vector_type(8))) short short8;
typedef __attribute__((ext_vector_type(4))) float f32x4;

union U4S8 { uint4 u; short8 s; };

__device__ __forceinline__ u32 f2bf(float x){            // RNE f32 -> bf16 bits
  u32 u = __float_as_uint(x);
  return (u + 0x7FFFu + ((u >> 16) & 1u)) >> 16;
}

// ---------------- u64 wave-wide bitonic helpers (key = (mapped_d<<13)|idx) ----------------
__device__ __forceinline__ void cx(u64 &k, int j, bool up, int lane){
  u64 o = __shfl_xor(k, j, 64);
  bool lower = (lane & j) == 0;
  bool take = (up == lower) ? (o < k) : (o > k);
  if (take) k = o;
}
__device__ __forceinline__ void sort64(u64 &k, int lane){
  #pragma unroll
  for (int kk = 2; kk <= 64; kk <<= 1){
    #pragma unroll
    for (int j = kk >> 1; j > 0; j >>= 1) cx(k, j, (lane & kk) == 0, lane);
  }
}
__device__ __forceinline__ void merge32(u64 &k, int lane){   // lanes 0..31 carry payload
  #pragma unroll
  for (int j = 16; j > 0; j >>= 1) cx(k, j, true, lane);
}

// ---------------- Kernel A: exact top-32 selection, 2 queries per wave ----------------
// Grid 2048 blocks -> 8 blocks/CU -> full 32 waves/CU occupancy (was grid-capped at 4).
__global__ __launch_bounds__(256) void kp_select(const float* __restrict__ xyz,
                                                 int* __restrict__ nbr){
  __shared__ u64 buf[4][2][128];           // per-wave per-query candidate buffer, 8 KB

  const int tid = threadIdx.x, w = tid >> 6, lane = tid & 63;
  const int qbase = blockIdx.x * 8 + w * 2;
  const int b = qbase >> 13;
  const float* base = xyz + (size_t)b * S_ * 3;

  float qx[2], qy[2], qz[2], sqq[2];
  #pragma unroll
  for (int i = 0; i < 2; ++i){
    int s = (qbase + i) & (S_ - 1);
    qx[i] = base[s*3]; qy[i] = base[s*3+1]; qz[i] = base[s*3+2];
    sqq[i] = qx[i]*qx[i] + qy[i]*qy[i] + qz[i]*qz[i];
  }

  u64 rkey[2] = {~0ull, ~0ull};            // lanes 0..31: running top-32 ascending
  // threshold init at mapped(R^2)=mapped(1.0f): beyond-radius candidates are
  // masked to idx0 downstream, so they never need to enter the top-32.
  u32 kmd[2]  = {0xBF800000u, 0xBF800000u};
  int cnt[2]  = {0, 0};

  // L2-resident point stream with next-chunk prefetch (xyz = 96 KB/batch)
  float cxv = base[lane*3], cyv = base[lane*3+1], czv = base[lane*3+2];

  for (int ch = 0; ch < 128; ++ch){
    float nxv = cxv, nyv = cyv, nzv = czv;
    if (ch < 127){
      int p = (ch + 1) * 64 + lane;
      nxv = base[p*3]; nyv = base[p*3+1]; nzv = base[p*3+2];
    }
    float sqp = cxv*cxv + cyv*cyv + czv*czv;
    int pidx = ch * 64 + lane;
    #pragma unroll
    for (int i = 0; i < 2; ++i){
      float dot = qx[i]*cxv + qy[i]*cyv + qz[i]*czv;
      float d = -2.0f * dot; d = d + sqq[i]; d = d + sqp;   // reference formula/order
      u32 md = __float_as_uint(d);
      md ^= (u32)((int)md >> 31) | 0x80000000u;            // monotonic float->uint map
      bool pred = md <= kmd[i];                            // ties pass (safe/conservative)
      u64 m = __ballot(pred);
      if (m){
        int pos = cnt[i] + (int)__popcll(m & ((1ull << lane) - 1ull));
        if (pred) buf[w][i][pos] = ((u64)md << 13) | (u32)pidx;
        cnt[i] += (int)__popcll(m);
        if (cnt[i] >= 64){
          cnt[i] -= 64;
          asm volatile("s_waitcnt lgkmcnt(0)" ::: "memory");
          u64 ck = buf[w][i][cnt[i] + lane];
          sort64(ck, lane);                                // chunk ascending
          u64 rev = __shfl(ck, (31 - lane) & 63, 64);      // best-32 reversed into lanes 0..31
          if (rev < rkey[i]) rkey[i] = rev;                // elementwise min -> bitonic
          merge32(rkey[i], lane);                          // 32 smallest of union
          u64 k31 = __shfl(rkey[i], 31, 64);
          kmd[i] = (u32)(k31 >> 13);
        }
      }
    }
    cxv = nxv; cyv = nyv; czv = nzv;
  }

  #pragma unroll
  for (int i = 0; i < 2; ++i){
    if (cnt[i] > 0){                               // final partial flush
      asm volatile("s_waitcnt lgkmcnt(0)" ::: "memory");
      u64 ck = (lane < cnt[i]) ? buf[w][i][lane] : ~0ull;
      sort64(ck, lane);
      u64 rev = __shfl(ck, (31 - lane) & 63, 64);
      if (rev < rkey[i]) rkey[i] = rev;
      merge32(rkey[i], lane);
    }
    u32 md  = (u32)(rkey[i] >> 13);
    int idx = (int)(rkey[i] & 8191u);
    int i0  = __shfl(idx, 0, 64);
    int wi  = (md > 0xBF800000u) ? i0 : idx;       // d > RADIUS^2 -> nearest idx
    if (lane < NS_) nbr[(size_t)(qbase + i) * NS_ + lane] = wi;
  }
}

// ---------------- Kernel W: expand W[k][c][o] f32 into bf16 B-fragment order ----------------
// kc' = c*16 + k (k padded to 16 with 0), K' = 1024.
// Layout: wb[(((wo*32 + st)*64 + lane)*8 + i)] with kc' = st*32 + (lane>>4)*8 + i,
//         o = wo*16 + (lane&15)  -> one uint4 per lane per MFMA step.
__global__ void w_cvt(const float* __restrict__ w, u16* __restrict__ wb){
  int idx = blockIdx.x * 256 + threadIdx.x;        // 65536 total
  int i    = idx & 7;
  int lane = (idx >> 3) & 63;
  int st   = (idx >> 9) & 31;
  int wo   = idx >> 14;
  int kc   = st * 32 + (lane >> 4) * 8 + i;
  int k    = kc & 15, c = kc >> 4;
  int o    = wo * 16 + (lane & 15);
  float v  = (k < K_) ? w[(k * 64 + c) * 64 + o] : 0.0f;
  wb[idx] = (u16)f2bf(v);
}

// ---------------- Kernel B: VALU aggregation + MFMA contraction ----------------
__global__ __launch_bounds__(256) void kp_gather(
    const float* __restrict__ xyz, const float* __restrict__ feat,
    const float* __restrict__ kp, const u16* __restrict__ wb,
    const int* __restrict__ nbr, float* __restrict__ outp){
  // A tile: 16 rows (q) x 1024 bf16 (kc') = 32 KB, 16B-granule XOR swizzle (g ^= row)
  __shared__ u32 aggA[16 * 512];

  const int tid = threadIdx.x, w = tid >> 6, lane = tid & 63;
  const int qbase = blockIdx.x * 16;
  const int b = qbase >> 13;
  const float* bx = xyz + (size_t)b * S_ * 3;
  const float* fb = feat + (size_t)b * S_ * CIN_;

  const int kk = lane & 15;
  float kx = 0.f, ky = 0.f, kz = 0.f;
  if (kk < 15){ kx = kp[kk*3]; ky = kp[kk*3+1]; kz = kp[kk*3+2]; }

  float agg0[15], agg1[15];

  auto do_q = [&](int ql, float (&agg)[15]){
    const int q = qbase + ql;
    const int s = q & (S_ - 1);
    const float qx = bx[s*3], qy = bx[s*3+1], qz = bx[s*3+2];
    int nl = 0; float nx = 0.f, ny = 0.f, nz = 0.f;
    if (lane < NS_){
      nl = nbr[(size_t)q * NS_ + lane];
      nx = bx[nl*3]; ny = bx[nl*3+1]; nz = bx[nl*3+2];
    }
    const float rx = nx - qx, ry = ny - qy, rz = nz - qz;

    // influences, (j,k)-lane-parallel: lane = ((j&3)<<4)|k
    float infl[8];
    #pragma unroll
    for (int jg = 0; jg < 8; ++jg){
      int jj = jg * 4 + (lane >> 4);
      float ax = __shfl(rx, jj, 64), ay = __shfl(ry, jj, 64), az = __shfl(rz, jj, 64);
      float dx = ax - kx, dy = ay - ky, dz = az - kz;
      float sq = dx*dx + dy*dy + dz*dz;
      sq = fmaxf(sq, 0.0f);
      infl[jg] = fmaxf(1.0f - sqrtf(sq + 1e-8f), 0.0f);   // /(R+1e-8) == /1.0f in f32
    }
    #pragma unroll
    for (int k = 0; k < 15; ++k) agg[k] = 0.0f;
    #pragma unroll
    for (int jg = 0; jg < 8; ++jg){
      int n0 = __shfl(nl, jg*4+0, 64); float f0 = fb[(size_t)n0 * CIN_ + lane];
      int n1 = __shfl(nl, jg*4+1, 64); float f1 = fb[(size_t)n1 * CIN_ + lane];
      int n2 = __shfl(nl, jg*4+2, 64); float f2 = fb[(size_t)n2 * CIN_ + lane];
      int n3 = __shfl(nl, jg*4+3, 64); float f3 = fb[(size_t)n3 * CIN_ + lane];
      u32 iv = __float_as_uint(infl[jg]);
      #pragma unroll
      for (int k = 0; k < 15; ++k){
        float s0 = __uint_as_float(__builtin_amdgcn_readlane(iv, k));
        float s1 = __uint_as_float(__builtin_amdgcn_readlane(iv, 16 + k));
        float s2 = __uint_as_float(__builtin_amdgcn_readlane(iv, 32 + k));
        float s3 = __uint_as_float(__builtin_amdgcn_readlane(iv, 48 + k));
        agg[k] = fmaf(s0, f0, agg[k]);
        agg[k] = fmaf(s1, f1, agg[k]);
        agg[k] = fmaf(s2, f2, agg[k]);
        agg[k] = fmaf(s3, f3, agg[k]);
      }
    }
  };

  // A-row store: lane c owns kc' = c*16 .. c*16+15 (its own agg[0..14] + zero pad)
  auto store_row = [&](int r, float (&agg)[15]){
    u32 pd[8];
    #pragma unroll
    for (int j = 0; j < 7; ++j) pd[j] = (f2bf(agg[2*j+1]) << 16) | f2bf(agg[2*j]);
    pd[7] = f2bf(agg[14]);                          // high bf16 = +0 pad
    u32* rp = aggA + r * 512;
    int g0 = (lane * 2)     ^ r;                    // 16B-granule XOR swizzle
    int g1 = (lane * 2 + 1) ^ r;
    uint4 v0; v0.x = pd[0]; v0.y = pd[1]; v0.z = pd[2]; v0.w = pd[3];
    uint4 v1; v1.x = pd[4]; v1.y = pd[5]; v1.z = pd[6]; v1.w = pd[7];
    *(uint4*)(rp + g0 * 4) = v0;
    *(uint4*)(rp + g1 * 4) = v1;
  };

  #pragma unroll
  for (int pair = 0; pair < 2; ++pair){
    do_q(w * 4 + pair * 2 + 0, agg0);
    do_q(w * 4 + pair * 2 + 1, agg1);
    store_row(w * 4 + pair * 2 + 0, agg0);
    store_row(w * 4 + pair * 2 + 1, agg1);
  }
  __syncthreads();

  // out[16q x 64o] = A[16 x 1024] @ Wb[1024 x 64]; wave w owns o-block w*16..w*16+15
  const int r  = lane & 15;                        // A row / D col-in-tile
  const int kb = lane >> 4;                        // k-block 0..3
  f32x4 acc = {0.f, 0.f, 0.f, 0.f};
  const uint4* wb4 = (const uint4*)wb + (size_t)(w * 32) * 64 + lane;
  u32* rp = aggA + r * 512;
  #pragma unroll
  for (int st = 0; st < 32; ++st){
    int gp = (st * 4 + kb) ^ r;
    U4S8 a; a.u = *(const uint4*)(rp + gp * 4);
    U4S8 bfr; bfr.u = wb4[st * 64];
    acc = __builtin_amdgcn_mfma_f32_16x16x32_bf16(a.s, bfr.s, acc, 0, 0, 0);
  }
  #pragma unroll
  for (int j = 0; j < 4; ++j){                     // C/D: col=lane&15, row=(lane>>4)*4+j
    int row = kb * 4 + j;
    outp[(size_t)(qbase + row) * COUT_ + w * 16 + r] = acc[j];
  }
}

extern "C" void kernel_launch(void* const* d_in, const int* in_sizes, int n_in,
                              void* d_out, int out_size, void* d_ws, size_t ws_size,
                              hipStream_t stream) {
  const float* xyz  = (const float*)d_in[0];
  const float* feat = (const float*)d_in[1];
  const float* w    = (const float*)d_in[2];
  const float* kp   = (const float*)d_in[3];

  float* out = (float*)d_out;                         // [B*S*3 xyz][B*S*64 out]
  u16*   wb  = (u16*)d_ws;                            // 65536 bf16 (131072 B), frag-ordered
  int*   nbr = (int*)((char*)d_ws + 131072);          // 16384*32 ints

  hipMemcpyAsync(out, xyz, (size_t)B_ * S_ * 3 * sizeof(float),
                 hipMemcpyDeviceToDevice, stream);

  w_cvt<<<256, 256, 0, stream>>>(w, wb);
  kp_select<<<(B_ * S_) / 8, 256, 0, stream>>>(xyz, nbr);
  kp_gather<<<(B_ * S_) / 16, 256, 0, stream>>>(xyz, feat, kp, wb, nbr,
                                                out + (size_t)B_ * S_ * 3);
}

// Round 10
// 189.862 us; speedup vs baseline: 4.7690x; 1.2246x over previous
//
#include <hip/hip_runtime.h>

#define B_    2
#define S_    8192
#define CIN_  64
#define COUT_ 64
#define K_    15
#define NS_   32

typedef unsigned long long u64;
typedef unsigned int u32;
typedef unsigned short u16;
typedef __attribute__((ext_vector_type(8))) short short8;
typedef __attribute__((ext_vector_type(4))) float f32x4;

union U4S8 { uint4 u; short8 s; };

__device__ __forceinline__ u32 f2bf(float x){            // RNE f32 -> bf16 bits
  u32 u = __float_as_uint(x);
  return (u + 0x7FFFu + ((u >> 16) & 1u)) >> 16;
}

// ---------------- u64 wave-wide bitonic helpers (key = (mapped_d<<13)|idx) ----------------
__device__ __forceinline__ void cx(u64 &k, int j, bool up, int lane){
  u64 o = __shfl_xor(k, j, 64);
  bool lower = (lane & j) == 0;
  bool take = (up == lower) ? (o < k) : (o > k);
  if (take) k = o;
}
__device__ __forceinline__ void sort64(u64 &k, int lane){
  #pragma unroll
  for (int kk = 2; kk <= 64; kk <<= 1){
    #pragma unroll
    for (int j = kk >> 1; j > 0; j >>= 1) cx(k, j, (lane & kk) == 0, lane);
  }
}
__device__ __forceinline__ void merge32(u64 &k, int lane){   // lanes 0..31 carry payload
  #pragma unroll
  for (int j = 16; j > 0; j >>= 1) cx(k, j, true, lane);
}

// ---------------- Kernel A: exact top-32 selection, 2 queries per wave ----------------
__global__ __launch_bounds__(256) void kp_select(const float* __restrict__ xyz,
                                                 int* __restrict__ nbr){
  __shared__ u64 buf[4][2][128];           // per-wave per-query candidate buffer, 8 KB

  const int tid = threadIdx.x, w = tid >> 6, lane = tid & 63;
  const int qbase = blockIdx.x * 8 + w * 2;
  const int b = qbase >> 13;
  const float* base = xyz + (size_t)b * S_ * 3;

  float qx[2], qy[2], qz[2], sqq[2];
  #pragma unroll
  for (int i = 0; i < 2; ++i){
    int s = (qbase + i) & (S_ - 1);
    qx[i] = base[s*3]; qy[i] = base[s*3+1]; qz[i] = base[s*3+2];
    sqq[i] = qx[i]*qx[i] + qy[i]*qy[i] + qz[i]*qz[i];
  }

  u64 rkey[2] = {~0ull, ~0ull};            // lanes 0..31: running top-32 ascending
  u32 kmd[2]  = {0xBF800000u, 0xBF800000u};  // threshold init at mapped(R^2)
  int cnt[2]  = {0, 0};

  float cxv = base[lane*3], cyv = base[lane*3+1], czv = base[lane*3+2];

  for (int ch = 0; ch < 128; ++ch){
    float nxv = cxv, nyv = cyv, nzv = czv;
    if (ch < 127){
      int p = (ch + 1) * 64 + lane;
      nxv = base[p*3]; nyv = base[p*3+1]; nzv = base[p*3+2];
    }
    float sqp = cxv*cxv + cyv*cyv + czv*czv;
    int pidx = ch * 64 + lane;
    #pragma unroll
    for (int i = 0; i < 2; ++i){
      float dot = qx[i]*cxv + qy[i]*cyv + qz[i]*czv;
      float d = -2.0f * dot; d = d + sqq[i]; d = d + sqp;   // reference formula/order
      u32 md = __float_as_uint(d);
      md ^= (u32)((int)md >> 31) | 0x80000000u;            // monotonic float->uint map
      bool pred = md <= kmd[i];                            // ties pass (safe/conservative)
      u64 m = __ballot(pred);
      if (m){
        int pos = cnt[i] + (int)__popcll(m & ((1ull << lane) - 1ull));
        if (pred) buf[w][i][pos] = ((u64)md << 13) | (u32)pidx;
        cnt[i] += (int)__popcll(m);
        if (cnt[i] >= 64){
          cnt[i] -= 64;
          asm volatile("s_waitcnt lgkmcnt(0)" ::: "memory");
          u64 ck = buf[w][i][cnt[i] + lane];
          sort64(ck, lane);                                // chunk ascending
          u64 rev = __shfl(ck, (31 - lane) & 63, 64);      // best-32 reversed into lanes 0..31
          if (rev < rkey[i]) rkey[i] = rev;                // elementwise min -> bitonic
          merge32(rkey[i], lane);                          // 32 smallest of union
          u64 k31 = __shfl(rkey[i], 31, 64);
          kmd[i] = (u32)(k31 >> 13);
        }
      }
    }
    cxv = nxv; cyv = nyv; czv = nzv;
  }

  #pragma unroll
  for (int i = 0; i < 2; ++i){
    if (cnt[i] > 0){                               // final partial flush
      asm volatile("s_waitcnt lgkmcnt(0)" ::: "memory");
      u64 ck = (lane < cnt[i]) ? buf[w][i][lane] : ~0ull;
      sort64(ck, lane);
      u64 rev = __shfl(ck, (31 - lane) & 63, 64);
      if (rev < rkey[i]) rkey[i] = rev;
      merge32(rkey[i], lane);
    }
    u32 md  = (u32)(rkey[i] >> 13);
    int idx = (int)(rkey[i] & 8191u);
    int i0  = __shfl(idx, 0, 64);
    int wi  = (md > 0xBF800000u) ? i0 : idx;       // d > RADIUS^2 -> nearest idx
    if (lane < NS_) nbr[(size_t)(qbase + i) * NS_ + lane] = wi;
  }
}

// ---------------- Kernel W: expand W[k][c][o] f32 into bf16 B-fragment order ----------------
__global__ void w_cvt(const float* __restrict__ w, u16* __restrict__ wb){
  int idx = blockIdx.x * 256 + threadIdx.x;        // 65536 total
  int i    = idx & 7;
  int lane = (idx >> 3) & 63;
  int st   = (idx >> 9) & 31;
  int wo   = idx >> 14;
  int kc   = st * 32 + (lane >> 4) * 8 + i;
  int k    = kc & 15, c = kc >> 4;
  int o    = wo * 16 + (lane & 15);
  float v  = (k < K_) ? w[(k * 64 + c) * 64 + o] : 0.0f;
  wb[idx] = (u16)f2bf(v);
}

// ---------------- Kernel B: VALU aggregation (8 waves, 2 q/wave) + MFMA contraction ----------------
__global__ __launch_bounds__(512, 7) void kp_gather(
    const float* __restrict__ xyz, const float* __restrict__ feat,
    const float* __restrict__ kp, const u16* __restrict__ wb,
    const int* __restrict__ nbr, float* __restrict__ outp){
  // A tile: 16 rows (q) x 1024 bf16 (kc') = 32 KB, 16B-granule XOR swizzle (g ^= row)
  __shared__ u32 aggA[16 * 512];
  __shared__ float red[4 * 64 * 4];                // K-half partial C, 4 KB

  const int tid = threadIdx.x, w = tid >> 6, lane = tid & 63;
  const int qbase = blockIdx.x * 16;
  const int b = qbase >> 13;
  const float* bx = xyz + (size_t)b * S_ * 3;
  const float* fb = feat + (size_t)b * S_ * CIN_;

  const int kk = lane & 15;
  float kx = 0.f, ky = 0.f, kz = 0.f;
  if (kk < 15){ kx = kp[kk*3]; ky = kp[kk*3+1]; kz = kp[kk*3+2]; }

  float agg[15];

  auto do_q = [&](int ql){
    const int q = qbase + ql;
    const int s = q & (S_ - 1);
    const float qx = bx[s*3], qy = bx[s*3+1], qz = bx[s*3+2];
    int nl = 0; float nx = 0.f, ny = 0.f, nz = 0.f;
    if (lane < NS_){
      nl = nbr[(size_t)q * NS_ + lane];
      nx = bx[nl*3]; ny = bx[nl*3+1]; nz = bx[nl*3+2];
    }
    const float rx = nx - qx, ry = ny - qy, rz = nz - qz;

    // influences, (j,k)-lane-parallel: lane = ((j&3)<<4)|k
    float infl[8];
    #pragma unroll
    for (int jg = 0; jg < 8; ++jg){
      int jj = jg * 4 + (lane >> 4);
      float ax = __shfl(rx, jj, 64), ay = __shfl(ry, jj, 64), az = __shfl(rz, jj, 64);
      float dx = ax - kx, dy = ay - ky, dz = az - kz;
      float sq = dx*dx + dy*dy + dz*dz;
      sq = fmaxf(sq, 0.0f);
      infl[jg] = fmaxf(1.0f - sqrtf(sq + 1e-8f), 0.0f);   // /(R+1e-8) == /1.0f in f32
    }
    #pragma unroll
    for (int k = 0; k < 15; ++k) agg[k] = 0.0f;

    // 1-deep prefetch of the next 4 neighbor feature rows
    int   nn[4]; float ff[4];
    #pragma unroll
    for (int t = 0; t < 4; ++t) nn[t] = __shfl(nl, t, 64);
    #pragma unroll
    for (int t = 0; t < 4; ++t) ff[t] = fb[(size_t)nn[t] * CIN_ + lane];

    #pragma unroll
    for (int jg = 0; jg < 8; ++jg){
      float f0 = ff[0], f1 = ff[1], f2 = ff[2], f3 = ff[3];
      if (jg < 7){
        #pragma unroll
        for (int t = 0; t < 4; ++t) nn[t] = __shfl(nl, (jg + 1) * 4 + t, 64);
        #pragma unroll
        for (int t = 0; t < 4; ++t) ff[t] = fb[(size_t)nn[t] * CIN_ + lane];
      }
      u32 iv = __float_as_uint(infl[jg]);
      #pragma unroll
      for (int k = 0; k < 15; ++k){
        float s0 = __uint_as_float(__builtin_amdgcn_readlane(iv, k));
        float s1 = __uint_as_float(__builtin_amdgcn_readlane(iv, 16 + k));
        float s2 = __uint_as_float(__builtin_amdgcn_readlane(iv, 32 + k));
        float s3 = __uint_as_float(__builtin_amdgcn_readlane(iv, 48 + k));
        agg[k] = fmaf(s0, f0, agg[k]);
        agg[k] = fmaf(s1, f1, agg[k]);
        agg[k] = fmaf(s2, f2, agg[k]);
        agg[k] = fmaf(s3, f3, agg[k]);
      }
    }
  };

  // A-row store: lane c owns kc' = c*16 .. c*16+15 (its own agg[0..14] + zero pad)
  auto store_row = [&](int r){
    u32 pd[8];
    #pragma unroll
    for (int j = 0; j < 7; ++j) pd[j] = (f2bf(agg[2*j+1]) << 16) | f2bf(agg[2*j]);
    pd[7] = f2bf(agg[14]);                          // high bf16 = +0 pad
    u32* rp = aggA + r * 512;
    int g0 = (lane * 2)     ^ r;                    // 16B-granule XOR swizzle
    int g1 = (lane * 2 + 1) ^ r;
    uint4 v0; v0.x = pd[0]; v0.y = pd[1]; v0.z = pd[2]; v0.w = pd[3];
    uint4 v1; v1.x = pd[4]; v1.y = pd[5]; v1.z = pd[6]; v1.w = pd[7];
    *(uint4*)(rp + g0 * 4) = v0;
    *(uint4*)(rp + g1 * 4) = v1;
  };

  do_q(w * 2 + 0); store_row(w * 2 + 0);
  do_q(w * 2 + 1); store_row(w * 2 + 1);
  __syncthreads();

  // out[16q x 64o] = A[16 x 1024] @ Wb[1024 x 64]
  // wave w: o-block ob = w&3 (cols ob*16..+15), K-half kh = w>>2 (512 each)
  const int r  = lane & 15;                        // A row / D col-in-tile
  const int kb = lane >> 4;                        // k-block 0..3
  const int ob = w & 3, kh = w >> 2;
  f32x4 acc = {0.f, 0.f, 0.f, 0.f};
  const uint4* wb4 = (const uint4*)wb + (size_t)(ob * 32 + kh * 16) * 64 + lane;
  u32* rp = aggA + r * 512;
  #pragma unroll
  for (int sp = 0; sp < 16; ++sp){
    int st = kh * 16 + sp;
    int gp = (st * 4 + kb) ^ r;
    U4S8 a; a.u = *(const uint4*)(rp + gp * 4);
    U4S8 bfr; bfr.u = wb4[sp * 64];
    acc = __builtin_amdgcn_mfma_f32_16x16x32_bf16(a.s, bfr.s, acc, 0, 0, 0);
  }
  if (kh == 1) *(f32x4*)&red[(ob * 64 + lane) * 4] = acc;
  __syncthreads();
  if (kh == 0){
    const float4 p = *(const float4*)&red[(ob * 64 + lane) * 4];
    #pragma unroll
    for (int j = 0; j < 4; ++j){                   // C/D: col=lane&15, row=(lane>>4)*4+j
      int row = kb * 4 + j;
      outp[(size_t)(qbase + row) * COUT_ + ob * 16 + r] = acc[j] + (&p.x)[j];
    }
  }
}

extern "C" void kernel_launch(void* const* d_in, const int* in_sizes, int n_in,
                              void* d_out, int out_size, void* d_ws, size_t ws_size,
                              hipStream_t stream) {
  const float* xyz  = (const float*)d_in[0];
  const float* feat = (const float*)d_in[1];
  const float* w    = (const float*)d_in[2];
  const float* kp   = (const float*)d_in[3];

  float* out = (float*)d_out;                         // [B*S*3 xyz][B*S*64 out]
  u16*   wb  = (u16*)d_ws;                            // 65536 bf16 (131072 B), frag-ordered
  int*   nbr = (int*)((char*)d_ws + 131072);          // 16384*32 ints

  hipMemcpyAsync(out, xyz, (size_t)B_ * S_ * 3 * sizeof(float),
                 hipMemcpyDeviceToDevice, stream);

  w_cvt<<<256, 256, 0, stream>>>(w, wb);
  kp_select<<<(B_ * S_) / 8, 256, 0, stream>>>(xyz, nbr);
  kp_gather<<<(B_ * S_) / 16, 512, 0, stream>>>(xyz, feat, kp, wb, nbr,
                                                out + (size_t)B_ * S_ * 3);
}